// Round 2
// baseline (346.477 us; speedup 1.0000x reference)
//
#include <hip/hip_runtime.h>
#include <math.h>

// Problem constants (B=4, S=2048, D=1024, O=512, T=16, depth=4)
#define TOK   8192
#define DD    1024
#define TT    16
#define NI    15
#define NL    16
#define OO    512
#define NC    256   // 240 decision rows + 16 gate rows

// workspace layout (floats): gate rows Wg[16][1024], then bias[240], invt[240]
#define WG_OFF   0
#define WG_SZ    (TT*DD)          // 16384 floats
#define PAR_OFF  (WG_OFF + WG_SZ) // +480 floats  => ~67KB total

// ---------------------------------------------------------------------------
// Prep: transpose gate_w (1024x16 -> 16x1024) and precompute per-node
// bias + 1/softplus-temperature.  Tiny (~67KB of ws).
// ---------------------------------------------------------------------------
__global__ __launch_bounds__(256) void k_prep(
    const float* __restrict__ db, const float* __restrict__ gw,
    const float* __restrict__ ntl, float* __restrict__ ws) {
  const int bid = blockIdx.x, tid = threadIdx.x;
  if (bid < 16) {
    const int qid = bid * 256 + tid;   // 4096 quads of Wg
    const int t = qid >> 8;            // gate row (tree)
    const int k = (qid & 255) << 2;
    float4 v;
    v.x = gw[(k + 0) * TT + t];
    v.y = gw[(k + 1) * TT + t];
    v.z = gw[(k + 2) * TT + t];
    v.w = gw[(k + 3) * TT + t];
    *(float4*)&ws[WG_OFF + t * DD + k] = v;
  } else {
    if (tid < 240) {
      float v = ntl[tid] + 0.5413f;
      float sp = (v > 20.f) ? v : log1pf(expf(v));   // softplus
      ws[PAR_OFF + tid]       = db[tid];             // bias
      ws[PAR_OFF + 240 + tid] = 1.0f / sp;           // 1/(TEMP*softplus)
    }
  }
}

// ---------------------------------------------------------------------------
// Fused kernel: per block = 16 tokens.
//   Phase A: GEMM1  act[16][256] = x_tile[16][1024] @ Wc^T  (Wc rows 0..239
//            straight from decision_weights, rows 240..255 from ws gate rows)
//   Phase B: epilogue -> sigmoid/leaf-products/gate-softmax -> weff in LDS
//   Phase C: GEMM2  out_tile[16][512] = weff[16][256] @ leaf_outputs[256][512]
//   Phase D: LayerNorm -> global out
// LDS (55.5KB): xs 576 | Ws 9216 (reused: LO chunk 8192 / out tile 8192)
//               | act 4096 (reused: weff tile)
// ---------------------------------------------------------------------------
__global__ __launch_bounds__(256, 2) void k_fused(
    const float* __restrict__ x, const float* __restrict__ dw,
    const float* __restrict__ LO, const float* __restrict__ gate_b,
    const float* __restrict__ gamma, const float* __restrict__ beta,
    const float* __restrict__ ws_all, float* __restrict__ out) {
  const float* Wg      = ws_all + WG_OFF;
  const float* bias240 = ws_all + PAR_OFF;
  const float* invt240 = ws_all + PAR_OFF + 240;

  __shared__ float xs[16 * 36];    // x tile: 16 tok x 32 k, stride 36
  __shared__ float Ws[256 * 36];   // W tile (also LO chunk / out tile)
  __shared__ float act[16 * 256];  // logits tile (also weff tile)

  const int tid = threadIdx.x;
  const int m0  = blockIdx.x * 16;
  const int ng  = tid & 63;        // n = ng + 64*j
  const int wv  = tid >> 6;        // wave id

  // ---------------- Phase A: GEMM1 ----------------
  float acc[4][4];
#pragma unroll
  for (int i = 0; i < 4; ++i)
#pragma unroll
    for (int j = 0; j < 4; ++j) acc[i][j] = 0.f;

  const bool xact = tid < 128;
  const int xr = tid >> 3, xc = (tid & 7) << 2;
  float4 px;
  float4 pw[8];

  if (xact) px = *(const float4*)&x[(size_t)(m0 + xr) * DD + xc];
#pragma unroll
  for (int u = 0; u < 8; ++u) {
    const int idx = tid + (u << 8);
    const int r = idx >> 3, c = (idx & 7) << 2;
    const float* src = (r < 240) ? (dw + (size_t)r * DD) : (Wg + (size_t)(r - 240) * DD);
    pw[u] = *(const float4*)&src[c];
  }

  for (int kc = 0; kc < DD; kc += 32) {
    if (xact) *(float4*)&xs[xr * 36 + xc] = px;
#pragma unroll
    for (int u = 0; u < 8; ++u) {
      const int idx = tid + (u << 8);
      const int r = idx >> 3, c = (idx & 7) << 2;
      *(float4*)&Ws[r * 36 + c] = pw[u];
    }
    __syncthreads();
    if (kc + 32 < DD) {
      if (xact) px = *(const float4*)&x[(size_t)(m0 + xr) * DD + kc + 32 + xc];
#pragma unroll
      for (int u = 0; u < 8; ++u) {
        const int idx = tid + (u << 8);
        const int r = idx >> 3, c = (idx & 7) << 2;
        const float* src = (r < 240) ? (dw + (size_t)r * DD) : (Wg + (size_t)(r - 240) * DD);
        pw[u] = *(const float4*)&src[kc + 32 + c];
      }
    }
#pragma unroll
    for (int k4 = 0; k4 < 32; k4 += 4) {
      float4 a[4], b[4];
#pragma unroll
      for (int i = 0; i < 4; ++i) a[i] = *(const float4*)&xs[(wv + 4 * i) * 36 + k4];
#pragma unroll
      for (int j = 0; j < 4; ++j) b[j] = *(const float4*)&Ws[(ng + 64 * j) * 36 + k4];
#pragma unroll
      for (int i = 0; i < 4; ++i)
#pragma unroll
        for (int j = 0; j < 4; ++j) {
          acc[i][j] = fmaf(a[i].x, b[j].x,
                      fmaf(a[i].y, b[j].y,
                      fmaf(a[i].z, b[j].z,
                      fmaf(a[i].w, b[j].w, acc[i][j]))));
        }
    }
    __syncthreads();
  }

  // scatter logits into act
#pragma unroll
  for (int i = 0; i < 4; ++i)
#pragma unroll
    for (int j = 0; j < 4; ++j)
      act[(wv + 4 * i) * 256 + ng + 64 * j] = acc[i][j];
  __syncthreads();

  // prefetch first LO chunk while epilogue runs
  float4 pl[8];
#pragma unroll
  for (int u = 0; u < 8; ++u) {
    const int f = tid + u * 256;
    pl[u] = *(const float4*)&LO[(size_t)f * 4];
  }

  // ---------------- Phase B: forest epilogue ----------------
  const int lane = tid & 63;
  const int sub  = lane >> 4;
  const int tr   = lane & 15;          // tree
  const int tl   = wv * 4 + sub;       // token local 0..15
  const float* arow = &act[tl * 256];

  float dec[15];
#pragma unroll
  for (int i = 0; i < 15; ++i) {
    const int ci = tr * 15 + i;
    float z = (arow[ci] + bias240[ci]) * invt240[ci];
    dec[i] = 1.f / (1.f + expf(-z));
  }
  float gl = arow[240 + tr] + gate_b[tr];
  float gmax = gl;
#pragma unroll
  for (int msk = 8; msk >= 1; msk >>= 1) gmax = fmaxf(gmax, __shfl_xor(gmax, msk, 16));
  float ge = expf(gl - gmax);
  float gsum = ge;
#pragma unroll
  for (int msk = 8; msk >= 1; msk >>= 1) gsum += __shfl_xor(gsum, msk, 16);
  const float gate = ge / gsum;

  float lp[16];
#pragma unroll
  for (int l = 0; l < 16; ++l) {
    float p = gate;
    int node = 0;
#pragma unroll
    for (int d = 0; d < 4; ++d) {
      const int bit = (l >> (3 - d)) & 1;
      p *= bit ? (1.f - dec[node]) : dec[node];
      node = 2 * node + 1 + bit;
    }
    lp[l] = p;
  }
  __syncthreads();   // all reads of act done before in-place overwrite
  float* wrow = &act[tl * 256 + tr * NL];
#pragma unroll
  for (int u = 0; u < 4; ++u)
    *(float4*)&wrow[u * 4] =
        make_float4(lp[u * 4], lp[u * 4 + 1], lp[u * 4 + 2], lp[u * 4 + 3]);
  __syncthreads();   // weff tile ready; Ws region now free

  // ---------------- Phase C: GEMM2 ----------------
  float* Ls = Ws;                      // reuse: LO chunk buffer (16x512)
  const int q = tid & 127;             // o-quad
  const int h = tid >> 7;              // token half

  float oacc[8][4];
#pragma unroll
  for (int i = 0; i < 8; ++i)
#pragma unroll
    for (int c = 0; c < 4; ++c) oacc[i][c] = 0.f;

  for (int kc = 0; kc < NC; kc += 16) {
#pragma unroll
    for (int u = 0; u < 8; ++u) {
      const int f = tid + u * 256;
      *(float4*)&Ls[f * 4] = pl[u];
    }
    __syncthreads();
    if (kc + 16 < NC) {
#pragma unroll
      for (int u = 0; u < 8; ++u) {
        const int f = tid + u * 256;
        pl[u] = *(const float4*)&LO[(size_t)(kc + 16) * OO + f * 4];
      }
    }
#pragma unroll
    for (int k4 = 0; k4 < 16; k4 += 4) {
      const float4 b0 = *(const float4*)&Ls[(k4 + 0) * OO + q * 4];
      const float4 b1 = *(const float4*)&Ls[(k4 + 1) * OO + q * 4];
      const float4 b2 = *(const float4*)&Ls[(k4 + 2) * OO + q * 4];
      const float4 b3 = *(const float4*)&Ls[(k4 + 3) * OO + q * 4];
#pragma unroll
      for (int i = 0; i < 8; ++i) {
        const float4 av = *(const float4*)&act[(h * 8 + i) * 256 + kc + k4];
        oacc[i][0] = fmaf(av.x, b0.x, fmaf(av.y, b1.x, fmaf(av.z, b2.x, fmaf(av.w, b3.x, oacc[i][0]))));
        oacc[i][1] = fmaf(av.x, b0.y, fmaf(av.y, b1.y, fmaf(av.z, b2.y, fmaf(av.w, b3.y, oacc[i][1]))));
        oacc[i][2] = fmaf(av.x, b0.z, fmaf(av.y, b1.z, fmaf(av.z, b2.z, fmaf(av.w, b3.z, oacc[i][2]))));
        oacc[i][3] = fmaf(av.x, b0.w, fmaf(av.y, b1.w, fmaf(av.z, b2.w, fmaf(av.w, b3.w, oacc[i][3]))));
      }
    }
    __syncthreads();
  }

  // out tile into Ls (Ws region)
#pragma unroll
  for (int i = 0; i < 8; ++i)
    *(float4*)&Ls[(h * 8 + i) * OO + q * 4] =
        make_float4(oacc[i][0], oacc[i][1], oacc[i][2], oacc[i][3]);
  __syncthreads();

  // ---------------- Phase D: LayerNorm ----------------
#pragma unroll
  for (int p = 0; p < 4; ++p) {
    const int t2 = wv * 4 + p;
    const float* row = &Ls[t2 * OO];
    const float4 v0 = *(const float4*)&row[lane * 8];
    const float4 v1 = *(const float4*)&row[lane * 8 + 4];
    float s  = v0.x + v0.y + v0.z + v0.w + v1.x + v1.y + v1.z + v1.w;
    float sq = v0.x * v0.x + v0.y * v0.y + v0.z * v0.z + v0.w * v0.w +
               v1.x * v1.x + v1.y * v1.y + v1.z * v1.z + v1.w * v1.w;
#pragma unroll
    for (int msk = 32; msk >= 1; msk >>= 1) {
      s  += __shfl_xor(s, msk, 64);
      sq += __shfl_xor(sq, msk, 64);
    }
    const float mu  = s * (1.f / 512.f);
    const float var = sq * (1.f / 512.f) - mu * mu;
    const float rs  = rsqrtf(var + 1e-5f);
    const float4 g0 = *(const float4*)&gamma[lane * 8];
    const float4 g1 = *(const float4*)&gamma[lane * 8 + 4];
    const float4 bb0 = *(const float4*)&beta[lane * 8];
    const float4 bb1 = *(const float4*)&beta[lane * 8 + 4];
    float4 o0, o1;
    o0.x = (v0.x - mu) * rs * g0.x + bb0.x;
    o0.y = (v0.y - mu) * rs * g0.y + bb0.y;
    o0.z = (v0.z - mu) * rs * g0.z + bb0.z;
    o0.w = (v0.w - mu) * rs * g0.w + bb0.w;
    o1.x = (v1.x - mu) * rs * g1.x + bb1.x;
    o1.y = (v1.y - mu) * rs * g1.y + bb1.y;
    o1.z = (v1.z - mu) * rs * g1.z + bb1.z;
    o1.w = (v1.w - mu) * rs * g1.w + bb1.w;
    float* orow = &out[(size_t)(m0 + t2) * OO + lane * 8];
    *(float4*)&orow[0] = o0;
    *(float4*)&orow[4] = o1;
  }
}

// ---------------------------------------------------------------------------
extern "C" void kernel_launch(void* const* d_in, const int* in_sizes, int n_in,
                              void* d_out, int out_size, void* d_ws, size_t ws_size,
                              hipStream_t stream) {
  const float* x   = (const float*)d_in[0];  // (4,2048,1024)
  const float* dw  = (const float*)d_in[1];  // (16,15,1024) == Wc rows 0..239
  const float* db  = (const float*)d_in[2];  // (16,15)
  const float* lo  = (const float*)d_in[3];  // (16,16,512) == LO[256][512]
  const float* gw  = (const float*)d_in[4];  // (1024,16)
  const float* gb  = (const float*)d_in[5];  // (16,)
  const float* ntl = (const float*)d_in[6];  // (16,15)
  const float* g   = (const float*)d_in[7];  // (512,)
  const float* b   = (const float*)d_in[8];  // (512,)
  float* ws  = (float*)d_ws;
  float* out = (float*)d_out;

  k_prep<<<17, 256, 0, stream>>>(db, gw, ntl, ws);
  k_fused<<<512, 256, 0, stream>>>(x, dw, lo, gb, g, b, ws, out);
}

// Round 3
// 186.190 us; speedup vs baseline: 1.8609x; 1.8609x over previous
//
#include <hip/hip_runtime.h>
#include <math.h>

// Problem constants (B=4, S=2048, D=1024, O=512, T=16, depth=4)
#define TOK 8192
#define DD  1024
#define OO  512
#define NC  256   // 240 decision rows + 16 gate rows

// ---- workspace byte layout (total ~1.5MB; d_ws is far larger per WRITE_SIZE evidence)
#define WC_HI_OFF  0                       // ushort[256][1024]
#define WC_LO_OFF  (512*1024)              // ushort[256][1024]
#define LOT_HI_OFF (1024*1024)             // ushort[512][256]  (LO transposed: [o][k])
#define LOT_LO_OFF (1024*1024 + 256*1024)  // ushort[512][256]
#define PAR_OFF_B  (1536*1024)             // float bias[240], invt[240]

typedef __attribute__((ext_vector_type(8))) short short8;
typedef __attribute__((ext_vector_type(4))) float f32x4;

#define MFMA16(a,b,c) __builtin_amdgcn_mfma_f32_16x16x32_bf16((a),(b),(c),0,0,0)

__device__ __forceinline__ ushort f2bh(float f) {   // f32 -> bf16 RNE
  union { float f; unsigned u; } v; v.f = f;
  unsigned r = v.u + 0x7fffu + ((v.u >> 16) & 1u);
  return (ushort)(r >> 16);
}
__device__ __forceinline__ float bh2f(ushort h) {
  union { unsigned u; float f; } v; v.u = ((unsigned)h) << 16; return v.f;
}
__device__ __forceinline__ void split2(float f, ushort& h, ushort& l) {
  h = f2bh(f);
  l = f2bh(f - bh2f(h));
}

// ---------------------------------------------------------------------------
// Prep: split-bf16 conversion of combined weights.
//  Wc rows 0..239 = decision_weights, 240..255 = gate_w^T.  LO_T[o][k].
// ---------------------------------------------------------------------------
__global__ __launch_bounds__(256) void k_prep(
    const float* __restrict__ dw, const float* __restrict__ db,
    const float* __restrict__ lo_in, const float* __restrict__ gw,
    const float* __restrict__ ntl, char* __restrict__ ws) {
  const int bid = blockIdx.x, tid = threadIdx.x;
  ushort* wch = (ushort*)(ws + WC_HI_OFF);
  ushort* wcl = (ushort*)(ws + WC_LO_OFF);
  ushort* lth = (ushort*)(ws + LOT_HI_OFF);
  ushort* ltl = (ushort*)(ws + LOT_LO_OFF);
  float*  par = (float*)(ws + PAR_OFF_B);

  if (bid < 256) {                       // Wc: 65536 quads
    const int idx = bid * 256 + tid;
    const int n = idx >> 8, k4 = (idx & 255) << 2;
    float v[4];
    if (n < 240) {
      const float4 t = *(const float4*)&dw[(size_t)n * DD + k4];
      v[0] = t.x; v[1] = t.y; v[2] = t.z; v[3] = t.w;
    } else {
      const int t = n - 240;
#pragma unroll
      for (int c = 0; c < 4; ++c) v[c] = gw[(size_t)(k4 + c) * 16 + t];
    }
    ushort4 h, l;
    split2(v[0], h.x, l.x); split2(v[1], h.y, l.y);
    split2(v[2], h.z, l.z); split2(v[3], h.w, l.w);
    *(ushort4*)&wch[(size_t)n * DD + k4] = h;
    *(ushort4*)&wcl[(size_t)n * DD + k4] = l;
  } else if (bid < 384) {                // LO_T: 32768 quads (along k)
    const int idx = (bid - 256) * 256 + tid;
    const int o = idx >> 6, k4 = (idx & 63) << 2;
    float v[4];
#pragma unroll
    for (int c = 0; c < 4; ++c) v[c] = lo_in[(size_t)(k4 + c) * OO + o];
    ushort4 h, l;
    split2(v[0], h.x, l.x); split2(v[1], h.y, l.y);
    split2(v[2], h.z, l.z); split2(v[3], h.w, l.w);
    *(ushort4*)&lth[(size_t)o * NC + k4] = h;
    *(ushort4*)&ltl[(size_t)o * NC + k4] = l;
  } else {
    if (tid < 240) {
      float v = ntl[tid] + 0.5413f;
      float sp = (v > 20.f) ? v : log1pf(expf(v));   // softplus
      par[tid]       = db[tid];
      par[240 + tid] = 1.0f / sp;
    }
  }
}

// ---------------------------------------------------------------------------
// Fused MFMA kernel: block = 32 tokens, 512 threads (8 waves), grid 256.
//  Phase A: logits[32][256] = x @ Wc^T  (split-bf16, 3-pass MFMA; B from L2)
//  Phase B: sigmoid / leaf products / gate softmax -> weff bf16 hi/lo in LDS
//  Phase C: out[32][512] = weff @ LO   (split-bf16, 3-pass MFMA; B from L2)
//  Phase D: LayerNorm in-register (1KB psum exchange) -> global out
// LDS 82432B: xs_hi 8K | xs_lo 8K | act 33.3K (f32 [32][260]) | wf_hi 16K | wf_lo 16K
// ---------------------------------------------------------------------------
#define XS_HI 0
#define XS_LO 8192
#define ACT_B 16384
#define WF_HI 49664
#define WF_LO 66048
#define SM_SZ 82432

__global__ __launch_bounds__(512, 2) void k_fused(
    const float* __restrict__ x, const char* __restrict__ ws,
    const float* __restrict__ gate_b, const float* __restrict__ gamma,
    const float* __restrict__ beta, float* __restrict__ out) {
  __shared__ __align__(16) char sm[SM_SZ];

  const char* wc_hi = ws + WC_HI_OFF;
  const char* wc_lo = ws + WC_LO_OFF;
  const char* lt_hi = ws + LOT_HI_OFF;
  const char* lt_lo = ws + LOT_LO_OFF;
  const float* par  = (const float*)(ws + PAR_OFF_B);

  const int tid  = threadIdx.x;
  const int wv   = tid >> 6;
  const int lane = tid & 63;
  const int mi   = wv >> 2;        // 0..1  (m-tile of 16 rows)
  const int nj   = wv & 3;         // 0..3  (n-quadrant)
  const int m0   = blockIdx.x * 32;
  const int l15  = lane & 15;
  const int kgrp = lane >> 4;      // 0..3

  // ================= Phase A: GEMM1 =================
  f32x4 acc[4];
#pragma unroll
  for (int j = 0; j < 4; ++j) acc[j] = (f32x4){0.f, 0.f, 0.f, 0.f};

  const int arow = mi * 16 + l15;

  for (int ch = 0; ch < 8; ++ch) {
    // stage+convert x chunk [32][128] f32 -> bf16 hi/lo, XOR-swizzled
#pragma unroll
    for (int u = 0; u < 2; ++u) {
      const int q = tid + u * 512;           // 0..1023
      const int m = q >> 5, kloc = (q & 31) << 2;
      const float4 v = *(const float4*)&x[(size_t)(m0 + m) * DD + ch * 128 + kloc];
      ushort4 h, l;
      split2(v.x, h.x, l.x); split2(v.y, h.y, l.y);
      split2(v.z, h.z, l.z); split2(v.w, h.w, l.w);
      const int off = (m * 256 + kloc * 2) ^ ((m & 7) << 4);
      *(ushort4*)(sm + XS_HI + off) = h;
      *(ushort4*)(sm + XS_LO + off) = l;
    }
    __syncthreads();
#pragma unroll
    for (int ks = 0; ks < 4; ++ks) {
      const int aoff = (arow * 256 + ks * 64 + kgrp * 16) ^ ((arow & 7) << 4);
      const short8 ah = *(const short8*)(sm + XS_HI + aoff);
      const short8 al = *(const short8*)(sm + XS_LO + aoff);
      const int kk2 = (ch * 128 + ks * 32 + kgrp * 8) * 2;   // byte k-offset
      short8 bh[4], bl[4];
#pragma unroll
      for (int j = 0; j < 4; ++j) {
        const int ncol = nj * 64 + j * 16 + l15;
        bh[j] = *(const short8*)(wc_hi + (size_t)ncol * 2048 + kk2);
        bl[j] = *(const short8*)(wc_lo + (size_t)ncol * 2048 + kk2);
      }
#pragma unroll
      for (int j = 0; j < 4; ++j) {
        acc[j] = MFMA16(ah, bh[j], acc[j]);
        acc[j] = MFMA16(ah, bl[j], acc[j]);
        acc[j] = MFMA16(al, bh[j], acc[j]);
      }
    }
    __syncthreads();
  }

  // scatter logits into act[32][260] f32
#pragma unroll
  for (int j = 0; j < 4; ++j)
#pragma unroll
    for (int r = 0; r < 4; ++r) {
      const int row = mi * 16 + kgrp * 4 + r;
      const int col = nj * 64 + j * 16 + l15;
      *(float*)(sm + ACT_B + (row * 260 + col) * 4) = acc[j][r];
    }
  __syncthreads();

  // ================= Phase B: forest epilogue =================
  {
    const int token = tid >> 4;      // 0..31
    const int tr    = tid & 15;      // tree
    const float* arow_p = (const float*)(sm + ACT_B + token * 260 * 4);

    float dec[15];
#pragma unroll
    for (int i = 0; i < 15; ++i) {
      const int ci = tr * 15 + i;
      const float z = (arow_p[ci] + par[ci]) * par[240 + ci];
      dec[i] = 1.f / (1.f + expf(-z));
    }
    float gl = arow_p[240 + tr] + gate_b[tr];
    float gmax = gl;
#pragma unroll
    for (int msk = 8; msk >= 1; msk >>= 1) gmax = fmaxf(gmax, __shfl_xor(gmax, msk, 16));
    const float ge = expf(gl - gmax);
    float gsum = ge;
#pragma unroll
    for (int msk = 8; msk >= 1; msk >>= 1) gsum += __shfl_xor(gsum, msk, 16);
    const float gate = ge / gsum;

    float lp[16];
#pragma unroll
    for (int l = 0; l < 16; ++l) {
      float p = gate;
      int node = 0;
#pragma unroll
      for (int d = 0; d < 4; ++d) {
        const int bit = (l >> (3 - d)) & 1;
        p *= bit ? (1.f - dec[node]) : dec[node];
        node = 2 * node + 1 + bit;
      }
      lp[l] = p;
    }
    // weff bf16 hi/lo, XOR-swizzled rows ([32][256] bf16, row = 512B)
    short8 h0, h1, l0, l1;
#pragma unroll
    for (int e = 0; e < 8; ++e) {
      ushort hh, ll;
      split2(lp[e], hh, ll);     h0[e] = (short)hh; l0[e] = (short)ll;
      split2(lp[8 + e], hh, ll); h1[e] = (short)hh; l1[e] = (short)ll;
    }
    const int b0 = (token * 512 + tr * 32) ^ ((token & 7) << 4);
    const int b1 = (token * 512 + tr * 32 + 16) ^ ((token & 7) << 4);
    *(short8*)(sm + WF_HI + b0) = h0;
    *(short8*)(sm + WF_HI + b1) = h1;
    *(short8*)(sm + WF_LO + b0) = l0;
    *(short8*)(sm + WF_LO + b1) = l1;
  }
  __syncthreads();

  // ================= Phase C: GEMM2 =================
  f32x4 acc2[8];
#pragma unroll
  for (int t = 0; t < 8; ++t) acc2[t] = (f32x4){0.f, 0.f, 0.f, 0.f};

  for (int ks = 0; ks < 8; ++ks) {
    const int aoff = (arow * 512 + ks * 64 + kgrp * 16) ^ ((arow & 7) << 4);
    const short8 ah = *(const short8*)(sm + WF_HI + aoff);
    const short8 al = *(const short8*)(sm + WF_LO + aoff);
    const int kk2 = (ks * 32 + kgrp * 8) * 2;
    short8 bh[8], bl[8];
#pragma unroll
    for (int t = 0; t < 8; ++t) {
      const int ocol = nj * 128 + t * 16 + l15;
      bh[t] = *(const short8*)(lt_hi + (size_t)ocol * 512 + kk2);
      bl[t] = *(const short8*)(lt_lo + (size_t)ocol * 512 + kk2);
    }
#pragma unroll
    for (int t = 0; t < 8; ++t) {
      acc2[t] = MFMA16(ah, bh[t], acc2[t]);
      acc2[t] = MFMA16(ah, bl[t], acc2[t]);
      acc2[t] = MFMA16(al, bh[t], acc2[t]);
    }
  }

  // ================= Phase D: LayerNorm (in-register) =================
  float s[4] = {0.f, 0.f, 0.f, 0.f}, sq[4] = {0.f, 0.f, 0.f, 0.f};
#pragma unroll
  for (int t = 0; t < 8; ++t)
#pragma unroll
    for (int r = 0; r < 4; ++r) {
      const float v = acc2[t][r];
      s[r] += v; sq[r] += v * v;
    }
#pragma unroll
  for (int msk = 8; msk >= 1; msk >>= 1)
#pragma unroll
    for (int r = 0; r < 4; ++r) {
      s[r]  += __shfl_xor(s[r], msk, 16);
      sq[r] += __shfl_xor(sq[r], msk, 16);
    }
  // cross-wave partials: psum[row][nj][2] f32 at sm[0..1K) (xs region free)
  float* ps = (float*)sm;
  if (l15 == 0) {
#pragma unroll
    for (int r = 0; r < 4; ++r) {
      const int row = mi * 16 + kgrp * 4 + r;
      ps[row * 8 + nj * 2 + 0] = s[r];
      ps[row * 8 + nj * 2 + 1] = sq[r];
    }
  }
  __syncthreads();

#pragma unroll
  for (int r = 0; r < 4; ++r) {
    const int row = mi * 16 + kgrp * 4 + r;
    float S = 0.f, Q = 0.f;
#pragma unroll
    for (int p = 0; p < 4; ++p) {
      S += ps[row * 8 + p * 2 + 0];
      Q += ps[row * 8 + p * 2 + 1];
    }
    const float mu  = S * (1.f / 512.f);
    const float var = Q * (1.f / 512.f) - mu * mu;
    const float rs  = rsqrtf(var + 1e-5f);
#pragma unroll
    for (int t = 0; t < 8; ++t) {
      const int col = nj * 128 + t * 16 + l15;
      const float v = (acc2[t][r] - mu) * rs * gamma[col] + beta[col];
      out[(size_t)(m0 + row) * OO + col] = v;
    }
  }
}

// ---------------------------------------------------------------------------
extern "C" void kernel_launch(void* const* d_in, const int* in_sizes, int n_in,
                              void* d_out, int out_size, void* d_ws, size_t ws_size,
                              hipStream_t stream) {
  const float* x   = (const float*)d_in[0];  // (4,2048,1024)
  const float* dw  = (const float*)d_in[1];  // (16,15,1024)
  const float* db  = (const float*)d_in[2];  // (16,15)
  const float* lo  = (const float*)d_in[3];  // (16,16,512)
  const float* gw  = (const float*)d_in[4];  // (1024,16)
  const float* gb  = (const float*)d_in[5];  // (16,)
  const float* ntl = (const float*)d_in[6];  // (16,15)
  const float* g   = (const float*)d_in[7];  // (512,)
  const float* b   = (const float*)d_in[8];  // (512,)
  char* ws   = (char*)d_ws;
  float* out = (float*)d_out;

  k_prep<<<385, 256, 0, stream>>>(dw, db, lo, gw, ntl, ws);
  k_fused<<<256, 512, 0, stream>>>(x, ws, gb, g, b, out);
}

// Round 4
// 121.683 us; speedup vs baseline: 2.8474x; 1.5301x over previous
//
#include <hip/hip_runtime.h>
#include <math.h>

// Problem constants (B=4, S=2048, D=1024, O=512, T=16, depth=4)
#define TOK 8192
#define DD  1024
#define OO  512
#define NC  256   // 240 decision rows + 16 gate rows

// ---- workspace byte layout (~1.5MB) ----
// Wc4: [128 k8][256 ncol] 16B units (8 consecutive k as bf16 per unit)
// LO4: [32 k8][512 ocol] 16B units
#define WC4_HI 0
#define WC4_LO (512*1024)
#define LO4_HI (1024*1024)
#define LO4_LO (1280*1024)
#define PAR_B  (1536*1024)   // f32 bias[240], invt[240]

typedef __attribute__((ext_vector_type(8))) short short8;
typedef __attribute__((ext_vector_type(4))) float f32x4;

#define MFMA16(a,b,c) __builtin_amdgcn_mfma_f32_16x16x32_bf16((a),(b),(c),0,0,0)

__device__ __forceinline__ ushort f2bh(float f) {   // f32 -> bf16 RNE
  union { float f; unsigned u; } v; v.f = f;
  unsigned r = v.u + 0x7fffu + ((v.u >> 16) & 1u);
  return (ushort)(r >> 16);
}
__device__ __forceinline__ float bh2f(ushort h) {
  union { unsigned u; float f; } v; v.u = ((unsigned)h) << 16; return v.f;
}
__device__ __forceinline__ void split2(float f, ushort& h, ushort& l) {
  h = f2bh(f);
  l = f2bh(f - bh2f(h));
}

// ---------------------------------------------------------------------------
// Prep: split-bf16 weights in channel-friendly [k8][col] 16B-unit layout.
// All reads and writes coalesced (lanes vary the fastest-moving dim).
// ---------------------------------------------------------------------------
__global__ __launch_bounds__(256) void k_prep(
    const float* __restrict__ dw, const float* __restrict__ db,
    const float* __restrict__ lo_in, const float* __restrict__ gw,
    const float* __restrict__ ntl, char* __restrict__ ws) {
  const int bid = blockIdx.x, tid = threadIdx.x;
  if (bid < 128) {                     // Wc: 256 ncol x 128 k8
    const int idx  = bid * 256 + tid;
    const int k8   = idx >> 8;         // 0..31 per 2 blocks? no: idx>>8 = bid  (k8 slow)
    const int ncol = idx & 255;        // lanes vary ncol -> coalesced writes
    float v[8];
    if (ncol < 240) {
#pragma unroll
      for (int c = 0; c < 8; ++c) v[c] = dw[(size_t)ncol * DD + k8 * 8 + c];
    } else {
      const int t = ncol - 240;
#pragma unroll
      for (int c = 0; c < 8; ++c) v[c] = gw[(size_t)(k8 * 8 + c) * 16 + t];
    }
    short8 h, l;
#pragma unroll
    for (int e = 0; e < 8; ++e) {
      ushort hh, ll; split2(v[e], hh, ll);
      h[e] = (short)hh; l[e] = (short)ll;
    }
    const size_t o16 = ((size_t)k8 * 256 + ncol) * 16;
    *(short8*)(ws + WC4_HI + o16) = h;
    *(short8*)(ws + WC4_LO + o16) = l;
  } else if (bid < 192) {              // LO: 512 ocol x 32 k8
    const int idx  = (bid - 128) * 256 + tid;   // 0..16383
    const int k8   = idx >> 9;         // 0..31
    const int ocol = idx & 511;        // lanes vary ocol -> coalesced both sides
    float v[8];
#pragma unroll
    for (int c = 0; c < 8; ++c) v[c] = lo_in[(size_t)(k8 * 8 + c) * OO + ocol];
    short8 h, l;
#pragma unroll
    for (int e = 0; e < 8; ++e) {
      ushort hh, ll; split2(v[e], hh, ll);
      h[e] = (short)hh; l[e] = (short)ll;
    }
    const size_t o16 = ((size_t)k8 * 512 + ocol) * 16;
    *(short8*)(ws + LO4_HI + o16) = h;
    *(short8*)(ws + LO4_LO + o16) = l;
  } else {
    if (tid < 240) {
      float v = ntl[tid] + 0.5413f;
      float sp = (v > 20.f) ? v : log1pf(expf(v));   // softplus
      float* par = (float*)(ws + PAR_B);
      par[tid]       = db[tid];
      par[240 + tid] = 1.0f / sp;
    }
  }
}

// ---------------------------------------------------------------------------
// Fused MFMA kernel: block = 32 tokens, 512 threads (8 waves), grid 256.
// Wave w owns 32 n-cols (GEMM1) / 64 o-cols (GEMM2) x all 32 rows.
// B streamed from L2 with contiguous lane addresses + 2-deep reg prefetch.
// LDS 64.5KB: xs dbuf 2x16K (act f32[32][260] overlays) | wf hi/lo 2x16K
// ---------------------------------------------------------------------------
#define XSB(b)  ((b) * 16384)      // per-buffer: HI at +0 (8K), LO at +8192
#define ACT_B   0                  // f32 [32][260] = 33280 B (overlays xs)
#define WF_HI   33280
#define WF_LO   49664
#define SM_SZ   66048

__global__ __launch_bounds__(512) void k_fused(
    const float* __restrict__ x, const char* __restrict__ ws,
    const float* __restrict__ gate_b, const float* __restrict__ gamma,
    const float* __restrict__ beta, float* __restrict__ out) {
  __shared__ __align__(16) char sm[SM_SZ];

  const char* wc4_hi = ws + WC4_HI;
  const char* wc4_lo = ws + WC4_LO;
  const char* lo4_hi = ws + LO4_HI;
  const char* lo4_lo = ws + LO4_LO;
  const float* par   = (const float*)(ws + PAR_B);

  const int tid  = threadIdx.x;
  const int wv   = tid >> 6;
  const int lane = tid & 63;
  const int l15  = lane & 15;
  const int kgrp = lane >> 4;        // 0..3
  const int m0   = blockIdx.x * 32;

  // ================= Phase A: GEMM1 =================
  f32x4 acc00 = {0,0,0,0}, acc01 = {0,0,0,0}, acc10 = {0,0,0,0}, acc11 = {0,0,0,0};
  short8 ah0, ah1, al0, al1;
  short8 bhE[2], blE[2], bhO[2], blO[2];
  float4 pxa, pxb;

  auto xload = [&](int CH) {
    const int m_ = tid >> 5, kl = (tid & 31) << 2;
    pxa = *(const float4*)&x[(size_t)(m0 + m_) * DD + CH * 128 + kl];
    pxb = *(const float4*)&x[(size_t)(m0 + 16 + m_) * DD + CH * 128 + kl];
  };
  auto xstore = [&](int BUF) {
    const int kl2 = ((tid & 31) << 2) * 2;
    ushort4 h, l;
    split2(pxa.x, h.x, l.x); split2(pxa.y, h.y, l.y);
    split2(pxa.z, h.z, l.z); split2(pxa.w, h.w, l.w);
    {
      const int m_ = tid >> 5;
      const int off = (m_ * 256 + kl2) ^ ((m_ & 7) << 4);
      *(ushort4*)(sm + XSB(BUF) + off) = h;
      *(ushort4*)(sm + XSB(BUF) + 8192 + off) = l;
    }
    split2(pxb.x, h.x, l.x); split2(pxb.y, h.y, l.y);
    split2(pxb.z, h.z, l.z); split2(pxb.w, h.w, l.w);
    {
      const int m_ = 16 + (tid >> 5);
      const int off = (m_ * 256 + kl2) ^ ((m_ & 7) << 4);
      *(ushort4*)(sm + XSB(BUF) + off) = h;
      *(ushort4*)(sm + XSB(BUF) + 8192 + off) = l;
    }
  };
  auto loadB1 = [&](int F, short8 (&BH)[2], short8 (&BL)[2]) {
    const size_t base = ((size_t)(F * 4 + kgrp) * 256) * 16;
#pragma unroll
    for (int j = 0; j < 2; ++j) {
      const size_t o = base + (size_t)(wv * 32 + j * 16 + l15) * 16;
      BH[j] = *(const short8*)(wc4_hi + o);
      BL[j] = *(const short8*)(wc4_lo + o);
    }
  };
  auto afrag = [&](int CB, int KS) {
    const int k0 = KS * 64 + kgrp * 16;
    const int a0 = (l15 * 256 + k0) ^ ((l15 & 7) << 4);
    const int a1 = ((16 + l15) * 256 + k0) ^ ((l15 & 7) << 4);
    ah0 = *(const short8*)(sm + XSB(CB) + a0);
    al0 = *(const short8*)(sm + XSB(CB) + 8192 + a0);
    ah1 = *(const short8*)(sm + XSB(CB) + a1);
    al1 = *(const short8*)(sm + XSB(CB) + 8192 + a1);
  };
  auto mfmaStep = [&](short8 (&BH)[2], short8 (&BL)[2]) {
    acc00 = MFMA16(ah0, BH[0], acc00); acc00 = MFMA16(ah0, BL[0], acc00);
    acc00 = MFMA16(al0, BH[0], acc00);
    acc01 = MFMA16(ah0, BH[1], acc01); acc01 = MFMA16(ah0, BL[1], acc01);
    acc01 = MFMA16(al0, BH[1], acc01);
    acc10 = MFMA16(ah1, BH[0], acc10); acc10 = MFMA16(ah1, BL[0], acc10);
    acc10 = MFMA16(al1, BH[0], acc10);
    acc11 = MFMA16(ah1, BH[1], acc11); acc11 = MFMA16(ah1, BL[1], acc11);
    acc11 = MFMA16(al1, BH[1], acc11);
  };

  // prologue
  xload(0);
  xstore(0);
  loadB1(0, bhE, blE);

  for (int ch = 0; ch < 8; ++ch) {
    __syncthreads();                 // xs(ch) visible to all waves
    const int cb = ch & 1;
    if (ch < 7) xload(ch + 1);       // HBM prefetch, hides under MFMAs
    const int f = ch * 4;
    afrag(cb, 0); loadB1(f + 1, bhO, blO); mfmaStep(bhE, blE);
    afrag(cb, 1); loadB1(f + 2, bhE, blE); mfmaStep(bhO, blO);
    afrag(cb, 2); loadB1(f + 3, bhO, blO); mfmaStep(bhE, blE);
    afrag(cb, 3); loadB1((f + 4 < 32) ? f + 4 : 31, bhE, blE); mfmaStep(bhO, blO);
    if (ch < 7) xstore(cb ^ 1);      // write NEXT buffer (no conflict w/ readers)
  }
  __syncthreads();

  // scatter logits into act f32[32][260] (overlays xs)
  {
    const f32x4 a[2][2] = {{acc00, acc01}, {acc10, acc11}};
#pragma unroll
    for (int mi = 0; mi < 2; ++mi)
#pragma unroll
      for (int j = 0; j < 2; ++j)
#pragma unroll
        for (int r = 0; r < 4; ++r) {
          const int row = mi * 16 + kgrp * 4 + r;
          const int col = wv * 32 + j * 16 + l15;
          *(float*)(sm + ACT_B + (row * 260 + col) * 4) = a[mi][j][r];
        }
  }
  __syncthreads();

  // GEMM2 B prologue (independent of LDS) — L2 latency hides under epilogue
  short8 cbhE[4], cblE[4], cbhO[4], cblO[4];
  auto loadB2 = [&](int F, short8 (&BH)[4], short8 (&BL)[4]) {
    const size_t base = ((size_t)(F * 4 + kgrp) * 512) * 16;
#pragma unroll
    for (int t = 0; t < 4; ++t) {
      const size_t o = base + (size_t)(wv * 64 + t * 16 + l15) * 16;
      BH[t] = *(const short8*)(lo4_hi + o);
      BL[t] = *(const short8*)(lo4_lo + o);
    }
  };
  loadB2(0, cbhE, cblE);

  // ================= Phase B: forest epilogue =================
  {
    const int token = tid >> 4;      // 0..31
    const int tr    = tid & 15;      // tree
    const float* arow_p = (const float*)(sm + ACT_B + token * 260 * 4);

    float dec[15];
#pragma unroll
    for (int i = 0; i < 15; ++i) {
      const int ci = tr * 15 + i;
      const float z = (arow_p[ci] + par[ci]) * par[240 + ci];
      dec[i] = 1.f / (1.f + expf(-z));
    }
    float gl = arow_p[240 + tr] + gate_b[tr];
    float gmax = gl;
#pragma unroll
    for (int msk = 8; msk >= 1; msk >>= 1) gmax = fmaxf(gmax, __shfl_xor(gmax, msk, 16));
    const float ge = expf(gl - gmax);
    float gsum = ge;
#pragma unroll
    for (int msk = 8; msk >= 1; msk >>= 1) gsum += __shfl_xor(gsum, msk, 16);
    const float gate = ge / gsum;

    float lp[16];
#pragma unroll
    for (int l = 0; l < 16; ++l) {
      float p = gate;
      int node = 0;
#pragma unroll
      for (int d = 0; d < 4; ++d) {
        const int bit = (l >> (3 - d)) & 1;
        p *= bit ? (1.f - dec[node]) : dec[node];
        node = 2 * node + 1 + bit;
      }
      lp[l] = p;
    }
    short8 h0, h1, l0, l1;
#pragma unroll
    for (int e = 0; e < 8; ++e) {
      ushort hh, ll;
      split2(lp[e], hh, ll);     h0[e] = (short)hh; l0[e] = (short)ll;
      split2(lp[8 + e], hh, ll); h1[e] = (short)hh; l1[e] = (short)ll;
    }
    const int b0 = (token * 512 + tr * 32) ^ ((token & 7) << 4);
    const int b1 = (token * 512 + tr * 32 + 16) ^ ((token & 7) << 4);
    *(short8*)(sm + WF_HI + b0) = h0;
    *(short8*)(sm + WF_HI + b1) = h1;
    *(short8*)(sm + WF_LO + b0) = l0;
    *(short8*)(sm + WF_LO + b1) = l1;
  }
  __syncthreads();

  // ================= Phase C: GEMM2 =================
  f32x4 ac0[4], ac1[4];
#pragma unroll
  for (int t = 0; t < 4; ++t) { ac0[t] = (f32x4){0,0,0,0}; ac1[t] = (f32x4){0,0,0,0}; }
  short8 wah0, wah1, wal0, wal1;
  auto wafrag = [&](int FC) {
    const int k0 = FC * 64 + kgrp * 16;
    const int a0 = (l15 * 512 + k0) ^ ((l15 & 7) << 4);
    const int a1 = ((16 + l15) * 512 + k0) ^ ((l15 & 7) << 4);
    wah0 = *(const short8*)(sm + WF_HI + a0);
    wal0 = *(const short8*)(sm + WF_LO + a0);
    wah1 = *(const short8*)(sm + WF_HI + a1);
    wal1 = *(const short8*)(sm + WF_LO + a1);
  };
  auto mfma2Step = [&](short8 (&BH)[4], short8 (&BL)[4]) {
#pragma unroll
    for (int t = 0; t < 4; ++t) {
      ac0[t] = MFMA16(wah0, BH[t], ac0[t]); ac0[t] = MFMA16(wah0, BL[t], ac0[t]);
      ac0[t] = MFMA16(wal0, BH[t], ac0[t]);
      ac1[t] = MFMA16(wah1, BH[t], ac1[t]); ac1[t] = MFMA16(wah1, BL[t], ac1[t]);
      ac1[t] = MFMA16(wal1, BH[t], ac1[t]);
    }
  };

#pragma unroll
  for (int it = 0; it < 4; ++it) {
    const int fe = it * 2;
    wafrag(fe);     loadB2(fe + 1, cbhO, cblO);                 mfma2Step(cbhE, cblE);
    wafrag(fe + 1); loadB2((fe + 2 < 8) ? fe + 2 : 7, cbhE, cblE); mfma2Step(cbhO, cblO);
  }

  // ================= Phase D: LayerNorm (in-register) =================
  float* ps = (float*)sm;    // [32 rows][8 waves][2] f32 = 2KB (act region dead)
#pragma unroll
  for (int mi = 0; mi < 2; ++mi)
#pragma unroll
    for (int r = 0; r < 4; ++r) {
      float s = 0.f, q = 0.f;
#pragma unroll
      for (int t = 0; t < 4; ++t) {
        const float v = (mi == 0) ? ac0[t][r] : ac1[t][r];
        s += v; q += v * v;
      }
#pragma unroll
      for (int msk = 8; msk >= 1; msk >>= 1) {
        s += __shfl_xor(s, msk, 16);
        q += __shfl_xor(q, msk, 16);
      }
      if (l15 == 0) {
        const int row = mi * 16 + kgrp * 4 + r;
        ps[(row * 8 + wv) * 2 + 0] = s;
        ps[(row * 8 + wv) * 2 + 1] = q;
      }
    }
  __syncthreads();

#pragma unroll
  for (int mi = 0; mi < 2; ++mi)
#pragma unroll
    for (int r = 0; r < 4; ++r) {
      const int row = mi * 16 + kgrp * 4 + r;
      float S = 0.f, Q = 0.f;
#pragma unroll
      for (int p = 0; p < 8; ++p) {
        S += ps[(row * 8 + p) * 2 + 0];
        Q += ps[(row * 8 + p) * 2 + 1];
      }
      const float mu  = S * (1.f / 512.f);
      const float var = Q * (1.f / 512.f) - mu * mu;
      const float rs  = rsqrtf(var + 1e-5f);
#pragma unroll
      for (int t = 0; t < 4; ++t) {
        const int col = wv * 64 + t * 16 + l15;
        const float v = (mi == 0) ? ac0[t][r] : ac1[t][r];
        out[(size_t)(m0 + row) * OO + col] = (v - mu) * rs * gamma[col] + beta[col];
      }
    }
}

// ---------------------------------------------------------------------------
extern "C" void kernel_launch(void* const* d_in, const int* in_sizes, int n_in,
                              void* d_out, int out_size, void* d_ws, size_t ws_size,
                              hipStream_t stream) {
  const float* x   = (const float*)d_in[0];  // (4,2048,1024)
  const float* dw  = (const float*)d_in[1];  // (16,15,1024)
  const float* db  = (const float*)d_in[2];  // (16,15)
  const float* lo  = (const float*)d_in[3];  // (16,16,512)
  const float* gw  = (const float*)d_in[4];  // (1024,16)
  const float* gb  = (const float*)d_in[5];  // (16,)
  const float* ntl = (const float*)d_in[6];  // (16,15)
  const float* g   = (const float*)d_in[7];  // (512,)
  const float* b   = (const float*)d_in[8];  // (512,)
  char* ws   = (char*)d_ws;
  float* out = (float*)d_out;

  k_prep<<<193, 256, 0, stream>>>(dw, db, lo, gw, ntl, ws);
  k_fused<<<256, 512, 0, stream>>>(x, ws, gb, g, b, out);
}